// Round 1
// baseline (24336.536 us; speedup 1.0000x reference)
//
#include <hip/hip_runtime.h>
#include <hip/hip_bf16.h>

#define T_STEPS 512
#define B_SZ    256
#define H_SZ    512
#define G3      1536

typedef __attribute__((ext_vector_type(8))) short short8;
typedef __attribute__((ext_vector_type(4))) float f32x4;

// Static device buffers: re-initialized by prep_kernel on EVERY launch
// (harness poisons d_ws, but these live in module BSS and we rewrite them).
__device__ unsigned int g_cnt[T_STEPS * 8];       // per-step, per-batch-group arrival count
__device__ float        g_keep[T_STEPS * B_SZ];   // 0.0 if reset at (t,b) else 1.0

__device__ __forceinline__ unsigned short f2b(float f) {
    return __builtin_bit_cast(unsigned short, __float2bfloat16(f));
}

// ---------------------------------------------------------------------------
// Prep: zero flags, detect resets dtype (bool bytes vs int32), build keep mask
// ---------------------------------------------------------------------------
__global__ void prep_kernel(const unsigned char* __restrict__ resets_raw) {
    __shared__ int s_isbyte;
    const int tid = threadIdx.x;
    if (tid == 0) s_isbyte = 0;

    // zero flags
    for (int i = tid; i < T_STEPS * 8; i += 1024) g_cnt[i] = 0u;
    __syncthreads();

    // detect: any nonzero byte at position %4 != 0  => byte-bool layout
    const int n = T_STEPS * B_SZ;   // 131072 elements
    int found = 0;
    for (int i = tid; i < n; i += 1024) {
        if ((i & 3) && resets_raw[i]) found = 1;
    }
    if (found) s_isbyte = 1;
    __syncthreads();
    const int isbyte = s_isbyte;

    const int* resets_i32 = (const int*)resets_raw;
    for (int i = tid; i < n; i += 1024) {
        bool r = isbyte ? (resets_raw[i] != 0) : (resets_i32[i] != 0);
        g_keep[i] = r ? 0.0f : 1.0f;
    }
}

// ---------------------------------------------------------------------------
// Swizzle ins (f32) -> bf16 in MFMA A-fragment layout:
//   xb[t][pb(8)][mt(2)][kt(16)][lane(64)][8]
//   lane l covers row = pb*32+mt*16+(l&15), k = kt*32+(l>>4)*8 .. +7
// ---------------------------------------------------------------------------
__global__ void swizzle_x(const float* __restrict__ ins, unsigned short* __restrict__ xb) {
    const int e = blockIdx.x * 256 + threadIdx.x;      // 0 .. 8388607
    const int lane = e & 63;
    const int kt   = (e >> 6) & 15;
    const int mt   = (e >> 10) & 1;
    const int pb   = (e >> 11) & 7;
    const int t    = e >> 14;

    const int row = pb * 32 + mt * 16 + (lane & 15);
    const int k   = kt * 32 + ((lane >> 4) << 3);
    const float* src = ins + ((size_t)(t * B_SZ + row)) * H_SZ + k;

    short8 v;
#pragma unroll
    for (int j = 0; j < 8; ++j) v[j] = (short)f2b(src[j]);
    *reinterpret_cast<short8*>(xb + (size_t)e * 8) = v;
}

// ---------------------------------------------------------------------------
// Persistent GRU kernel.
// Grid: 256 blocks = 8 batch-groups (pb) x 32 hidden-column blocks (pc).
// Block: 384 threads = 6 waves; wave w -> output tile (mt = w/3, nt = w%3).
// Each block owns batch rows [pb*32, +32), hidden cols [pc*16, +16), and keeps
// its Wi/Wh column slices (512 x 48 each, bf16) in LDS for all 512 steps.
// h exchange between the 32 blocks of a group goes through d_out (ys[t-1]).
// ---------------------------------------------------------------------------
__launch_bounds__(384, 1)
__global__ void gru_main(const float* __restrict__ ins,
                         const float* __restrict__ Wi,
                         const float* __restrict__ bi,
                         const float* __restrict__ Wh,
                         const float* __restrict__ bhn,
                         const unsigned short* __restrict__ xb,
                         int use_xb,
                         float* __restrict__ out) {
    __shared__ __align__(16) unsigned short lWi[3 * 16 * 64 * 8];  // 48 KB
    __shared__ __align__(16) unsigned short lWh[3 * 16 * 64 * 8];  // 48 KB
    __shared__ float sGi[32 * 48];    // 6 KB gather buffer (x gates)
    __shared__ float sGh[32 * 48];    // 6 KB gather buffer (h gates)
    __shared__ float sHp[32 * 16];    // 2 KB local copy of our h tile
    __shared__ float sBi[48];
    __shared__ float sBhn[16];

    const int tid  = threadIdx.x;
    const int pb   = blockIdx.x & 7;
    const int pc   = blockIdx.x >> 3;
    const int r0   = pb * 32;
    const int c0   = pc * 16;
    const int lane = tid & 63;
    const int w    = tid >> 6;      // 0..5
    const int mt   = (w >= 3) ? 1 : 0;
    const int nt   = w - mt * 3;    // 0..2 (gate chunk)

    // ---- stage Wi/Wh column slices into LDS as B-fragments (one-time) ----
    for (int idx = tid; idx < 3 * 16 * 64; idx += 384) {
        int snt = idx >> 10;
        int skt = (idx >> 6) & 15;
        int sl  = idx & 63;
        int col = snt * 512 + c0 + (sl & 15);
        int kb  = skt * 32 + ((sl >> 4) << 3);
#pragma unroll
        for (int j = 0; j < 8; ++j) {
            lWi[idx * 8 + j] = f2b(Wi[(size_t)(kb + j) * G3 + col]);
            lWh[idx * 8 + j] = f2b(Wh[(size_t)(kb + j) * G3 + col]);
        }
    }
    if (tid < 48) sBi[tid] = bi[(tid >> 4) * 512 + c0 + (tid & 15)];
    if (tid < 16) sBhn[tid] = bhn[c0 + tid];
    __syncthreads();

    const int arow  = (mt << 4) + (lane & 15);        // A-row within 32
    const int grow  = r0 + arow;                      // global batch row
    const int koff  = (lane >> 4) << 3;               // 0,8,16,24
    const int ccol  = lane & 15;                      // C col within 16
    const int crow0 = (mt << 4) + ((lane >> 4) << 2); // C row base within 32

    const short8* wip = reinterpret_cast<const short8*>(lWi) + nt * 16 * 64 + lane;
    const short8* whp = reinterpret_cast<const short8*>(lWh) + nt * 16 * 64 + lane;

    for (int t = 0; t < T_STEPS; ++t) {
        // ---- gi GEMM: x_t tile @ Wi slice (no recurrent dependency) ----
        f32x4 acc = {0.f, 0.f, 0.f, 0.f};
        if (use_xb) {
            const short8* xp = reinterpret_cast<const short8*>(
                xb + ((((size_t)t * 8 + pb) * 2 + mt) * 16) * 512) + lane;
#pragma unroll
            for (int kt = 0; kt < 16; ++kt) {
                short8 a = xp[kt * 64];
                short8 b = wip[kt * 64];
                acc = __builtin_amdgcn_mfma_f32_16x16x32_bf16(a, b, acc, 0, 0, 0);
            }
        } else {
            const float* xrow = ins + ((size_t)t * B_SZ + grow) * H_SZ + koff;
#pragma unroll
            for (int kt = 0; kt < 16; ++kt) {
                const float* p = xrow + kt * 32;
                short8 a;
#pragma unroll
                for (int j = 0; j < 8; ++j) a[j] = (short)f2b(p[j]);
                short8 b = wip[kt * 64];
                acc = __builtin_amdgcn_mfma_f32_16x16x32_bf16(a, b, acc, 0, 0, 0);
            }
        }

        // ---- gh GEMM: masked h_{t-1} @ Wh slice (critical path) ----
        f32x4 acch = {0.f, 0.f, 0.f, 0.f};
        if (t > 0) {
            unsigned int* cp = &g_cnt[(t - 1) * 8 + pb];
            int guard = 0;
            while (__hip_atomic_load(cp, __ATOMIC_ACQUIRE, __HIP_MEMORY_SCOPE_AGENT) < 32u) {
                __builtin_amdgcn_s_sleep(1);
                if (++guard > (1 << 26)) break;   // safety valve: fail loud, not hang
            }
            const float keep = g_keep[t * B_SZ + grow];
            const float* hrow = out + ((size_t)(t - 1) * B_SZ + grow) * H_SZ + koff;
#pragma unroll
            for (int kt = 0; kt < 16; ++kt) {
                const float* p = hrow + kt * 32;
                short8 a;
#pragma unroll
                for (int j = 0; j < 8; ++j) a[j] = (short)f2b(p[j] * keep);
                short8 b = whp[kt * 64];
                acch = __builtin_amdgcn_mfma_f32_16x16x32_bf16(a, b, acch, 0, 0, 0);
            }
        }

        // ---- gather accumulators to LDS ----
#pragma unroll
        for (int rg = 0; rg < 4; ++rg) {
            sGi[(crow0 + rg) * 48 + nt * 16 + ccol] = acc[rg];
            sGh[(crow0 + rg) * 48 + nt * 16 + ccol] = acch[rg];
        }
        __syncthreads();

        // ---- elementwise gates + h update + output write ----
        for (int idx = tid; idx < 512; idx += 384) {
            const int row = idx >> 4, j = idx & 15;
            const float xr = sGi[row * 48 + j]      + sBi[j];
            const float xz = sGi[row * 48 + 16 + j] + sBi[16 + j];
            const float xn = sGi[row * 48 + 32 + j] + sBi[32 + j];
            const float hr = sGh[row * 48 + j];
            const float hz = sGh[row * 48 + 16 + j];
            const float hn = sGh[row * 48 + 32 + j];
            const float rg = 1.f / (1.f + __expf(-(xr + hr)));
            const float zg = 1.f / (1.f + __expf(-(xz + hz)));
            const float ng = tanhf(xn + rg * (hn + sBhn[j]));
            float hp = 0.f;
            if (t > 0) {
                const float kp = g_keep[t * B_SZ + r0 + row];
                hp = sHp[idx] * kp;
            }
            const float hnew = (1.f - zg) * ng + zg * hp;
            sHp[idx] = hnew;   // same thread owns this slot every step
            out[((size_t)t * B_SZ + r0 + row) * H_SZ + c0 + j] = hnew;
        }

        // ---- publish: make our ys[t] slice visible, then signal ----
        __threadfence();
        __syncthreads();
        if (tid == 0)
            __hip_atomic_fetch_add(&g_cnt[t * 8 + pb], 1u,
                                   __ATOMIC_RELEASE, __HIP_MEMORY_SCOPE_AGENT);
    }
}

// ---------------------------------------------------------------------------
extern "C" void kernel_launch(void* const* d_in, const int* in_sizes, int n_in,
                              void* d_out, int out_size, void* d_ws, size_t ws_size,
                              hipStream_t stream) {
    const float* ins    = (const float*)d_in[0];
    const void*  resets = d_in[1];
    const float* Wi     = (const float*)d_in[2];
    const float* bi     = (const float*)d_in[3];
    const float* Wh     = (const float*)d_in[4];
    const float* bhn    = (const float*)d_in[5];
    float*       out    = (float*)d_out;

    prep_kernel<<<1, 1024, 0, stream>>>((const unsigned char*)resets);

    const size_t xb_bytes = (size_t)T_STEPS * B_SZ * H_SZ * sizeof(unsigned short);
    const int use_xb = (ws_size >= xb_bytes) ? 1 : 0;
    unsigned short* xb = (unsigned short*)d_ws;
    if (use_xb) {
        // 8,388,608 fragment-rows of 8 bf16 each
        swizzle_x<<<32768, 256, 0, stream>>>(ins, xb);
    }
    gru_main<<<256, 384, 0, stream>>>(ins, Wi, bi, Wh, bhn, xb, use_xb, out);
}

// Round 3
// 4557.967 us; speedup vs baseline: 5.3393x; 5.3393x over previous
//
#include <hip/hip_runtime.h>
#include <hip/hip_bf16.h>

#define T_STEPS 512
#define B_SZ    256
#define H_SZ    512
#define G3      1536
#define EX_DW   (B_SZ * H_SZ / 2)   // dwords per exchange slot (2 bf16 per dword)
#define NSLOT   4

typedef __attribute__((ext_vector_type(8))) short short8;
typedef __attribute__((ext_vector_type(4))) int   int4v;
typedef __attribute__((ext_vector_type(4))) float f32x4;

// Static device buffers, rewritten every launch (no reliance on prior state).
__device__ unsigned int g_cnt[T_STEPS * 8];           // per (t, batch-group) arrival count
__device__ float        g_keep[(T_STEPS + 1) * B_SZ]; // keep mask; row T is all-zero pad
__device__ unsigned int g_exch[NSLOT * EX_DW];        // bf16 h exchange, row-major [B][H]

__device__ __forceinline__ unsigned short f2b(float f) {
    return __builtin_bit_cast(unsigned short, __float2bfloat16(f));
}

// ---------------------------------------------------------------------------
// Prep: zero flags AT THE COHERENCE POINT (system-scope stores), build keep
// mask (plain stores — cross-kernel visibility via dispatch-boundary flush).
// ---------------------------------------------------------------------------
__global__ void prep_kernel(const unsigned char* __restrict__ resets_raw) {
    __shared__ int s_isbyte;
    const int tid = threadIdx.x;
    if (tid == 0) s_isbyte = 0;

    for (int i = tid; i < T_STEPS * 8; i += 1024)
        __hip_atomic_store(&g_cnt[i], 0u, __ATOMIC_RELAXED, __HIP_MEMORY_SCOPE_SYSTEM);
    __syncthreads();

    const int n = T_STEPS * B_SZ;
    int found = 0;
    for (int i = tid; i < n; i += 1024) {
        if ((i & 3) && resets_raw[i]) found = 1;
    }
    if (found) s_isbyte = 1;
    __syncthreads();
    const int isbyte = s_isbyte;

    const int* ri = (const int*)resets_raw;
    for (int i = tid; i < n; i += 1024) {
        bool r = isbyte ? (resets_raw[i] != 0) : (ri[i] != 0);
        g_keep[i] = r ? 0.0f : 1.0f;
    }
    for (int i = tid; i < B_SZ; i += 1024) g_keep[n + i] = 0.0f;  // t==T pad
}

// ---------------------------------------------------------------------------
// Persistent GRU. Grid 256 = 8 batch-groups (pb) x 32 col-blocks (pc).
// 384 threads = 6 waves = 2 mt x 3 nt output tiles. Weights resident in LDS.
// h exchange: bf16, pre-masked with keep[t+1], via g_exch slots (sc0 sc1,
// L3-coherent). Flags: relaxed system atomics. NO wbl2 / NO buffer_inv.
// ---------------------------------------------------------------------------
__launch_bounds__(384, 1)
__global__ void gru_main(const float* __restrict__ ins,
                         const float* __restrict__ Wi,
                         const float* __restrict__ bi,
                         const float* __restrict__ Wh,
                         const float* __restrict__ bhn,
                         float* __restrict__ out) {
    __shared__ __align__(16) unsigned short lWi[3 * 16 * 64 * 8];  // 48 KB
    __shared__ __align__(16) unsigned short lWh[3 * 16 * 64 * 8];  // 48 KB
    __shared__ __align__(16) unsigned short sHb[2 * 16 * 64 * 8];  // 32 KB h frags
    __shared__ float sGi[32 * 48];
    __shared__ float sGh[32 * 48];
    __shared__ float sHp[32 * 16];
    __shared__ float sBi[48];
    __shared__ float sBhn[16];

    const int tid  = threadIdx.x;
    const int pb   = blockIdx.x & 7;
    const int pc   = blockIdx.x >> 3;
    const int r0   = pb * 32;
    const int c0   = pc * 16;
    const int lane = tid & 63;
    const int w    = tid >> 6;
    const int mt   = (w >= 3) ? 1 : 0;
    const int nt   = w - mt * 3;

    // ---- one-time: stage Wi/Wh column slices as bf16 B-fragments ----
    for (int idx = tid; idx < 3 * 16 * 64; idx += 384) {
        int snt = idx >> 10, skt = (idx >> 6) & 15, sl = idx & 63;
        int col = snt * 512 + c0 + (sl & 15);
        int kb  = skt * 32 + ((sl >> 4) << 3);
#pragma unroll
        for (int j = 0; j < 8; ++j) {
            lWi[idx * 8 + j] = f2b(Wi[(size_t)(kb + j) * G3 + col]);
            lWh[idx * 8 + j] = f2b(Wh[(size_t)(kb + j) * G3 + col]);
        }
    }
    if (tid < 48) sBi[tid]  = bi[(tid >> 4) * 512 + c0 + (tid & 15)];
    if (tid < 16) sBhn[tid] = bhn[c0 + tid];
    for (int i = tid; i < 512; i += 384) sHp[i] = 0.0f;
    __syncthreads();

    const int grow  = r0 + mt * 16 + (lane & 15);      // A-frag global row
    const int koff  = (lane >> 4) << 3;                // 0,8,16,24
    const int ccol  = lane & 15;
    const int crow0 = (mt << 4) + ((lane >> 4) << 2);

    const short8* wip = (const short8*)lWi + nt * 16 * 64 + lane;
    const short8* whp = (const short8*)lWh + nt * 16 * 64 + lane;
    const short8* hbp = (const short8*)sHb + mt * 16 * 64 + lane;
    short8*       hbw = (short8*)sHb       + mt * 16 * 64 + lane;

    const bool loader = (nt == 0);   // waves 0 (mt0) and 3 (mt1)

    // ---- prologue: gi for t=0 ----
    f32x4 acc_gi = {0.f, 0.f, 0.f, 0.f};
    {
        const float* xrow = ins + (size_t)grow * H_SZ + koff;
#pragma unroll
        for (int kt = 0; kt < 16; ++kt) {
            const f32x4* p = (const f32x4*)(xrow + kt * 32);
            f32x4 x0 = p[0], x1 = p[1];
            short8 a;
#pragma unroll
            for (int j = 0; j < 4; ++j) { a[j] = (short)f2b(x0[j]); a[4 + j] = (short)f2b(x1[j]); }
            acc_gi = __builtin_amdgcn_mfma_f32_16x16x32_bf16(a, wip[kt * 64], acc_gi, 0, 0, 0);
        }
    }

    for (int t = 0; t < T_STEPS; ++t) {
        // ---- loader waves: wait for step t-1, pull h tile into LDS frags ----
        if (t > 0 && loader) {
            unsigned int* cp = &g_cnt[(t - 1) * 8 + pb];
            int guard = 0;
            while (__hip_atomic_load(cp, __ATOMIC_RELAXED, __HIP_MEMORY_SCOPE_SYSTEM) < 32u) {
                __builtin_amdgcn_s_sleep(1);
                if (++guard > (1 << 22)) break;   // fail loud, never hang
            }
            asm volatile("" ::: "memory");
            const char* ebase = (const char*)g_exch
                + (size_t)((t - 1) & (NSLOT - 1)) * (EX_DW * 4)
                + (size_t)grow * (H_SZ * 2) + koff * 2;
            int4v hf[16];
#pragma unroll
            for (int kt = 0; kt < 16; ++kt)
                asm volatile("global_load_dwordx4 %0, %1, off sc0 sc1"
                             : "=v"(hf[kt]) : "v"(ebase + kt * 64));
            asm volatile("s_waitcnt vmcnt(0)" ::: "memory");
            __builtin_amdgcn_sched_barrier(0);
#pragma unroll
            for (int kt = 0; kt < 16; ++kt)
                hbw[kt * 64] = __builtin_bit_cast(short8, hf[kt]);
        }
        __syncthreads();

        // ---- gh GEMM from LDS (h already masked by producer) ----
        f32x4 acch = {0.f, 0.f, 0.f, 0.f};
        if (t > 0) {
#pragma unroll
            for (int kt = 0; kt < 16; ++kt)
                acch = __builtin_amdgcn_mfma_f32_16x16x32_bf16(hbp[kt * 64], whp[kt * 64], acch, 0, 0, 0);
        }

        // ---- gather accumulators ----
#pragma unroll
        for (int rg = 0; rg < 4; ++rg) {
            sGi[(crow0 + rg) * 48 + nt * 16 + ccol] = acc_gi[rg];
            sGh[(crow0 + rg) * 48 + nt * 16 + ccol] = acch[rg];
        }
        __syncthreads();

        // ---- gates + h update; write out (f32) + exchange (bf16, pre-masked) ----
        if (tid < 256) {
            const int row = tid >> 3;
            const int j0  = (tid & 7) * 2;
            const int gr  = r0 + row;
            float hv[2];
#pragma unroll
            for (int u = 0; u < 2; ++u) {
                const int j = j0 + u;
                const float xr = sGi[row * 48 + j]      + sBi[j];
                const float xz = sGi[row * 48 + 16 + j] + sBi[16 + j];
                const float xn = sGi[row * 48 + 32 + j] + sBi[32 + j];
                const float hr = sGh[row * 48 + j];
                const float hz = sGh[row * 48 + 16 + j];
                const float hn = sGh[row * 48 + 32 + j];
                const float rg = 1.f / (1.f + __expf(-(xr + hr)));
                const float zg = 1.f / (1.f + __expf(-(xz + hz)));
                float targ = xn + rg * (hn + sBhn[j]);
                targ = fminf(15.f, fmaxf(-15.f, targ));
                const float e2 = __expf(-2.f * targ);
                const float ng = (1.f - e2) / (1.f + e2);          // tanh
                const float hp = sHp[row * 16 + j];                // pre-masked h_{t-1}
                hv[u] = (1.f - zg) * ng + zg * hp;
            }
            *(float2*)(out + ((size_t)t * B_SZ + gr) * H_SZ + c0 + j0) = make_float2(hv[0], hv[1]);
            const float kn  = g_keep[(t + 1) * B_SZ + gr];
            const float hm0 = hv[0] * kn, hm1 = hv[1] * kn;
            sHp[row * 16 + j0]     = hm0;
            sHp[row * 16 + j0 + 1] = hm1;
            const unsigned int pk = (unsigned int)f2b(hm0) | ((unsigned int)f2b(hm1) << 16);
            __hip_atomic_store(&g_exch[(t & (NSLOT - 1)) * EX_DW + gr * 256 + (c0 >> 1) + (tid & 7)],
                               pk, __ATOMIC_RELAXED, __HIP_MEMORY_SCOPE_SYSTEM);
        }
        asm volatile("s_waitcnt vmcnt(0)" ::: "memory");   // drain write-through stores
        __syncthreads();
        if (tid == 0)
            __hip_atomic_fetch_add(&g_cnt[t * 8 + pb], 1u,
                                   __ATOMIC_RELAXED, __HIP_MEMORY_SCOPE_SYSTEM);

        // ---- gi GEMM for t+1: issued AFTER our flag add, hides under spin ----
        if (t + 1 < T_STEPS) {
            const float* xrow = ins + ((size_t)(t + 1) * B_SZ + grow) * H_SZ + koff;
            f32x4 ag = {0.f, 0.f, 0.f, 0.f};
#pragma unroll
            for (int kt = 0; kt < 16; ++kt) {
                const f32x4* p = (const f32x4*)(xrow + kt * 32);
                f32x4 x0 = p[0], x1 = p[1];
                short8 a;
#pragma unroll
                for (int j = 0; j < 4; ++j) { a[j] = (short)f2b(x0[j]); a[4 + j] = (short)f2b(x1[j]); }
                ag = __builtin_amdgcn_mfma_f32_16x16x32_bf16(a, wip[kt * 64], ag, 0, 0, 0);
            }
            acc_gi = ag;
        }
    }
}

// ---------------------------------------------------------------------------
extern "C" void kernel_launch(void* const* d_in, const int* in_sizes, int n_in,
                              void* d_out, int out_size, void* d_ws, size_t ws_size,
                              hipStream_t stream) {
    const float* ins    = (const float*)d_in[0];
    const void*  resets = d_in[1];
    const float* Wi     = (const float*)d_in[2];
    const float* bi     = (const float*)d_in[3];
    const float* Wh     = (const float*)d_in[4];
    const float* bhn    = (const float*)d_in[5];
    float*       outp   = (float*)d_out;

    prep_kernel<<<1, 1024, 0, stream>>>((const unsigned char*)resets);
    gru_main<<<256, 384, 0, stream>>>(ins, Wi, bi, Wh, bhn, outp);
}

// Round 6
// 4374.935 us; speedup vs baseline: 5.5627x; 1.0418x over previous
//
#include <hip/hip_runtime.h>
#include <hip/hip_bf16.h>

#define T_STEPS 512
#define B_SZ    256
#define H_SZ    512
#define G3      1536

// Exchange: per row 96 chunks of 16B = {tag u32, 6 x bf16}; 2 slots.
#define CH_ROW      96
#define ROW_BYTES   (CH_ROW * 16)          // 1536
#define SLOT_BYTES  (B_SZ * ROW_BYTES)     // 393216
#define HR_STRIDE   520                    // shorts per LDS h row (16B-aligned: 1040B)

typedef __attribute__((ext_vector_type(8))) short short8;
typedef __attribute__((ext_vector_type(4))) int   int4v;
typedef __attribute__((ext_vector_type(4))) float f32x4;

// Static device state. Exchange tags are launch-id-qualified, so g_exch never
// needs clearing between launches/replays; prep only bumps g_launch.
__device__ unsigned int g_launch;
__device__ float        g_keep[(T_STEPS + 1) * B_SZ];
__device__ __align__(16) unsigned int g_exch[2 * SLOT_BYTES / 4];

__device__ __forceinline__ unsigned short f2b(float f) {
    return __builtin_bit_cast(unsigned short, __float2bfloat16(f));
}

// ---------------------------------------------------------------------------
__global__ void prep_kernel(const unsigned char* __restrict__ resets_raw) {
    __shared__ int s_isbyte;
    const int tid = threadIdx.x;
    if (tid == 0) {
        s_isbyte = 0;
        __hip_atomic_fetch_add(&g_launch, 1u, __ATOMIC_RELAXED, __HIP_MEMORY_SCOPE_SYSTEM);
    }
    __syncthreads();

    const int n = T_STEPS * B_SZ;
    int found = 0;
    for (int i = tid; i < n; i += 1024)
        if ((i & 3) && resets_raw[i]) found = 1;
    if (found) s_isbyte = 1;
    __syncthreads();
    const int isbyte = s_isbyte;

    const int* ri = (const int*)resets_raw;
    for (int i = tid; i < n; i += 1024) {
        bool r = isbyte ? (resets_raw[i] != 0) : (ri[i] != 0);
        g_keep[i] = r ? 0.0f : 1.0f;
    }
    for (int i = tid; i < B_SZ; i += 1024) g_keep[n + i] = 0.0f;  // t==T pad
}

// ---------------------------------------------------------------------------
// Persistent GRU. Grid 256 = 8 batch-groups (pb) x 32 col-blocks (pc).
// 384 threads = 6 waves = 2 mt x 3 nt tiles. Weights resident in LDS.
// h exchange: self-validating tagged 16B chunks {tag, 6 x bf16}, pre-masked
// with keep[t+1], via sc0 sc1 (coherence point). Data load IS the poll —
// no flags, no producer drain, no sleep quantization. Single mode only.
// ---------------------------------------------------------------------------
__launch_bounds__(384, 1)
__global__ void gru_main(const float* __restrict__ ins,
                         const float* __restrict__ Wi,
                         const float* __restrict__ bi,
                         const float* __restrict__ Wh,
                         const float* __restrict__ bhn,
                         float* __restrict__ out) {
    __shared__ __align__(16) unsigned short lWi[3 * 16 * 64 * 8];   // 48 KB
    __shared__ __align__(16) unsigned short lWh[3 * 16 * 64 * 8];   // 48 KB
    __shared__ __align__(16) unsigned short sHr[32 * HR_STRIDE];    // 32.5 KB row-major h
    __shared__ float sGi[32 * 48];
    __shared__ float sGh[32 * 48];
    __shared__ float sHp[32 * 16];
    __shared__ unsigned int sHx[32 * 8];    // packed bf16 pairs of masked h
    __shared__ float sBi[48];
    __shared__ float sBhn[16];
    __shared__ unsigned sLid;

    const int tid  = threadIdx.x;
    const int pb   = blockIdx.x & 7;
    const int pc   = blockIdx.x >> 3;
    const int r0   = pb * 32;
    const int c0   = pc * 16;
    const int lane = tid & 63;
    const int w    = tid >> 6;
    const int mt   = (w >= 3) ? 1 : 0;
    const int nt   = w - mt * 3;

    if (tid == 0) {
        unsigned lid_;
        const void* lp = (const void*)&g_launch;
        asm volatile("global_load_dword %0, %1, off sc0 sc1" : "=v"(lid_) : "v"(lp) : "memory");
        asm volatile("s_waitcnt vmcnt(0)" ::: "memory");
        sLid = lid_;
    }

    // ================= one-time weight staging ==============================
    for (int idx = tid; idx < 3 * 16 * 64; idx += 384) {
        int snt = idx >> 10, skt = (idx >> 6) & 15, sl = idx & 63;
        int col = snt * 512 + c0 + (sl & 15);
        int kb  = skt * 32 + ((sl >> 4) << 3);
#pragma unroll
        for (int j = 0; j < 8; ++j) {
            lWi[idx * 8 + j] = f2b(Wi[(size_t)(kb + j) * G3 + col]);
            lWh[idx * 8 + j] = f2b(Wh[(size_t)(kb + j) * G3 + col]);
        }
    }
    if (tid < 48) sBi[tid]  = bi[(tid >> 4) * 512 + c0 + (tid & 15)];
    if (tid < 16) sBhn[tid] = bhn[c0 + tid];
    for (int i = tid; i < 512; i += 384) sHp[i] = 0.0f;
    __syncthreads();
    const unsigned lid = sLid;

    const int grow = r0 + mt * 16 + (lane & 15);
    const int koff = (lane >> 4) << 3;
    const int ccol  = lane & 15;
    const int crow0 = (mt << 4) + ((lane >> 4) << 2);

    const short8* wip = (const short8*)lWi + nt * 16 * 64 + lane;
    const short8* whp = (const short8*)lWh + nt * 16 * 64 + lane;
    const short8* hfp = (const short8*)(sHr + (mt * 16 + (lane & 15)) * HR_STRIDE + koff);

    // Consumer chunk map: 8 chunks per thread (3072 per block), constants.
    unsigned gofs[8], ldo[8];
    bool ldn[8];
#pragma unroll
    for (int i = 0; i < 8; ++i) {
        const int q = tid + 384 * i;
        const int row = q / 96, g = q % 96;
        const int colbase = (g / 3) * 16 + (g % 3) * 6;
        gofs[i] = (unsigned)(((r0 + row) * 96 + g) * 16);
        ldo[i]  = (unsigned)(row * HR_STRIDE + colbase);     // short units
        ldn[i]  = ((g % 3) < 2);
    }
    // Producer chunk map (tid < 96).
    const int prow = tid / 3;
    const int pc3  = tid % 3;
    const size_t pofs = ((size_t)(r0 + prow) * 96 + pc * 3 + pc3) * 16;

    // ---- prologue: gi for t=0 ----
    f32x4 acc_gi = {0.f, 0.f, 0.f, 0.f};
    {
        const float* xrow = ins + (size_t)grow * H_SZ + koff;
#pragma unroll
        for (int kt = 0; kt < 16; ++kt) {
            const f32x4* p = (const f32x4*)(xrow + kt * 32);
            f32x4 x0 = p[0], x1 = p[1];
            short8 a;
#pragma unroll
            for (int j = 0; j < 4; ++j) { a[j] = (short)f2b(x0[j]); a[4 + j] = (short)f2b(x1[j]); }
            acc_gi = __builtin_amdgcn_mfma_f32_16x16x32_bf16(a, wip[kt * 64], acc_gi, 0, 0, 0);
        }
    }

    for (int t = 0; t < T_STEPS; ++t) {
        // ---- consume h_{t-1}: tagged-chunk retry loads -> LDS rows ----
        if (t > 0) {
            const unsigned want = (lid << 10) | (unsigned)t;
            const char* abase = (const char*)g_exch + (size_t)((t - 1) & 1) * SLOT_BYTES;
            int4v cv[8];
            unsigned pend = 0xFFu;
#pragma unroll
            for (int i = 0; i < 8; ++i) {
                const char* ap = abase + gofs[i];
                asm volatile("global_load_dwordx4 %0, %1, off sc0 sc1" : "=v"(cv[i]) : "v"(ap) : "memory");
            }
            int guard = 0;
            for (;;) {
                asm volatile("s_waitcnt vmcnt(0)" ::: "memory");
#pragma unroll
                for (int i = 0; i < 8; ++i) {
                    if ((pend >> i) & 1u) {
                        if ((unsigned)cv[i][0] == want) {
                            unsigned* lp = (unsigned*)(sHr + ldo[i]);
                            lp[0] = (unsigned)cv[i][1];
                            lp[1] = (unsigned)cv[i][2];
                            if (ldn[i]) lp[2] = (unsigned)cv[i][3];
                            pend &= ~(1u << i);
                        }
                    }
                }
                if (!pend) break;
                if (++guard > (1 << 22)) break;   // fail loud, never hang
#pragma unroll
                for (int i = 0; i < 8; ++i) {
                    if ((pend >> i) & 1u) {
                        const char* ap = abase + gofs[i];
                        asm volatile("global_load_dwordx4 %0, %1, off sc0 sc1" : "=v"(cv[i]) : "v"(ap) : "memory");
                    }
                }
            }
        }
        __syncthreads();   // B0: sHr ready; also fences sHx reuse

        // ---- gh GEMM from row-major LDS ----
        f32x4 acch = {0.f, 0.f, 0.f, 0.f};
        if (t > 0) {
#pragma unroll
            for (int kt = 0; kt < 16; ++kt)
                acch = __builtin_amdgcn_mfma_f32_16x16x32_bf16(hfp[kt * 4], whp[kt * 64], acch, 0, 0, 0);
        }

        // ---- gather ----
#pragma unroll
        for (int rg = 0; rg < 4; ++rg) {
            sGi[(crow0 + rg) * 48 + nt * 16 + ccol] = acc_gi[rg];
            sGh[(crow0 + rg) * 48 + nt * 16 + ccol] = acch[rg];
        }
        __syncthreads();   // B1

        // ---- gates + h update ----
        if (tid < 256) {
            const int row = tid >> 3;
            const int j0  = (tid & 7) * 2;
            const int gr  = r0 + row;
            float hv[2];
#pragma unroll
            for (int u = 0; u < 2; ++u) {
                const int j = j0 + u;
                const float xr = sGi[row * 48 + j]      + sBi[j];
                const float xz = sGi[row * 48 + 16 + j] + sBi[16 + j];
                const float xn = sGi[row * 48 + 32 + j] + sBi[32 + j];
                const float hr = sGh[row * 48 + j];
                const float hz = sGh[row * 48 + 16 + j];
                const float hn = sGh[row * 48 + 32 + j];
                const float rg = 1.f / (1.f + __expf(-(xr + hr)));
                const float zg = 1.f / (1.f + __expf(-(xz + hz)));
                float targ = xn + rg * (hn + sBhn[j]);
                targ = fminf(15.f, fmaxf(-15.f, targ));
                const float e2 = __expf(-2.f * targ);
                const float ng = (1.f - e2) / (1.f + e2);
                const float hp = sHp[row * 16 + j];
                hv[u] = (1.f - zg) * ng + zg * hp;
            }
            *(float2*)(out + ((size_t)t * B_SZ + gr) * H_SZ + c0 + j0) = make_float2(hv[0], hv[1]);
            const float kn  = g_keep[(t + 1) * B_SZ + gr];
            const float hm0 = hv[0] * kn, hm1 = hv[1] * kn;
            sHp[row * 16 + j0]     = hm0;
            sHp[row * 16 + j0 + 1] = hm1;
            sHx[row * 8 + (tid & 7)] = (unsigned)f2b(hm0) | ((unsigned)f2b(hm1) << 16);
        }
        __syncthreads();   // B2: sHx ready

        // ---- publish: self-validating tagged chunks (no flag, no drain) ----
        if (t + 1 < T_STEPS && tid < 96) {
            const unsigned tag = (lid << 10) | (unsigned)(t + 1);
            const unsigned p0 = sHx[prow * 8 + pc3 * 3];
            const unsigned p1 = sHx[prow * 8 + pc3 * 3 + 1];
            const unsigned p2 = (pc3 < 2) ? sHx[prow * 8 + pc3 * 3 + 2] : 0u;
            int4v d;
            d[0] = (int)tag; d[1] = (int)p0; d[2] = (int)p1; d[3] = (int)p2;
            const char* ap = (const char*)g_exch + (size_t)(t & 1) * SLOT_BYTES + pofs;
            asm volatile("global_store_dwordx4 %0, %1, off sc0 sc1" :: "v"(ap), "v"(d) : "memory");
        }

        // ---- gi GEMM for t+1 (overlaps the fabric round-trip) ----
        if (t + 1 < T_STEPS) {
            const float* xrow = ins + ((size_t)(t + 1) * B_SZ + grow) * H_SZ + koff;
            f32x4 ag = {0.f, 0.f, 0.f, 0.f};
#pragma unroll
            for (int kt = 0; kt < 16; ++kt) {
                const f32x4* p = (const f32x4*)(xrow + kt * 32);
                f32x4 x0 = p[0], x1 = p[1];
                short8 a;
#pragma unroll
                for (int j = 0; j < 4; ++j) { a[j] = (short)f2b(x0[j]); a[4 + j] = (short)f2b(x1[j]); }
                ag = __builtin_amdgcn_mfma_f32_16x16x32_bf16(a, wip[kt * 64], ag, 0, 0, 0);
            }
            acc_gi = ag;
        }
    }
}

// ---------------------------------------------------------------------------
extern "C" void kernel_launch(void* const* d_in, const int* in_sizes, int n_in,
                              void* d_out, int out_size, void* d_ws, size_t ws_size,
                              hipStream_t stream) {
    const float* ins    = (const float*)d_in[0];
    const void*  resets = d_in[1];
    const float* Wi     = (const float*)d_in[2];
    const float* bi     = (const float*)d_in[3];
    const float* Wh     = (const float*)d_in[4];
    const float* bhn    = (const float*)d_in[5];
    float*       outp   = (float*)d_out;

    prep_kernel<<<1, 1024, 0, stream>>>((const unsigned char*)resets);
    gru_main<<<256, 384, 0, stream>>>(ins, Wi, bi, Wh, bhn, outp);
}